// Round 6
// baseline (265.891 us; speedup 1.0000x reference)
//
#include <hip/hip_runtime.h>
#include <math.h>

#define B_ 8
#define P_ 32
#define S_ 512
#define D_ 64
#define NQS 4    // query splits per bp in the attention kernel

typedef __attribute__((ext_vector_type(8))) short short8;
typedef __attribute__((ext_vector_type(4))) float f32x4;

static __device__ inline unsigned short f2bf(float f) {
    // round-to-nearest-even fp32 -> bf16 (finite inputs only)
    unsigned u = __float_as_uint(f);
    unsigned r = (u + 0x7FFFu + ((u >> 16) & 1u)) >> 16;
    return (unsigned short)r;
}

// ---------------------------------------------------------------------------
// Kernel 1 (fused prep, grid 1024):
//  blocks [0,512):   E16[b,r,k] = bf16(exp(score(r,k)-2)), 8 rows/block.
//  blocks [512,1024): per (bp, half-K): Bprep = bf16(mask*x) in MFMA
//    B-fragment lane order (+ mask column tile ct=4), and out=x for mask=1
//    rows (copy phase lives here, where x is streamed anyway).
// Bprep layout: [bp][chunk c<8][kc2<2][ct<5][lane<64][8 shorts] (80 KB/bp).
// ---------------------------------------------------------------------------
__launch_bounds__(256)
__global__ void k_prep(const float* __restrict__ t, const float* __restrict__ alpha_w,
                       const float* __restrict__ x, const float* __restrict__ mask,
                       unsigned short* __restrict__ E16, unsigned short* __restrict__ Bprep,
                       float* __restrict__ out) {
    const int bid = blockIdx.x;
    const int tid = threadIdx.x, lane = tid & 63, wave = tid >> 6;

    __shared__ __align__(16) union {
        struct { float tpeT[16][S_]; float red[8]; } e;            // 32.8 KB
        struct { unsigned short xbT[64][72]; float maskL[S_]; } p; // 11.3 KB
    } sm;

    if (bid < 512) {
        // ================= E16 part =================
        const int b = bid >> 6;
        const int r0 = (bid & 63) * 8;

        float v0 = t[b * S_ + tid];
        float v1 = t[b * S_ + tid + 256];
        float mn = fminf(v0, v1), mx = fmaxf(v0, v1);
#pragma unroll
        for (int o = 32; o > 0; o >>= 1) {
            mn = fminf(mn, __shfl_xor(mn, o, 64));
            mx = fmaxf(mx, __shfl_xor(mx, o, 64));
        }
        if (lane == 0) { sm.e.red[wave] = mn; sm.e.red[4 + wave] = mx; }
        __syncthreads();
        mn = fminf(fminf(sm.e.red[0], sm.e.red[1]), fminf(sm.e.red[2], sm.e.red[3]));
        mx = fmaxf(fmaxf(sm.e.red[4], sm.e.red[5]), fmaxf(sm.e.red[6], sm.e.red[7]));

        float aw = alpha_w[0] * 1000.0f;
        float el = aw > 0.0f ? aw : (__expf(aw) - 1.0f);   // elu, alpha=1
        float inv = (el + 1.0f) / (mx - mn);

        const float divs[8] = {1.0f, 0.31622776601683794f, 0.1f, 0.031622776601683791f,
                               0.01f, 0.0031622776601683794f, 0.001f, 0.00031622776601683794f};
        {
            float tn0 = (v0 - mn) * inv;
            float tn1 = (v1 - mn) * inv;
#pragma unroll
            for (int f = 0; f < 8; f++) {
                float a0 = tn0 * divs[f], a1 = tn1 * divs[f];
                sm.e.tpeT[2 * f][tid]           = 0.5f * __sinf(a0);  // 0.5^2 folds /sqrt(16)
                sm.e.tpeT[2 * f + 1][tid]       = 0.5f * __cosf(a0);
                sm.e.tpeT[2 * f][tid + 256]     = 0.5f * __sinf(a1);
                sm.e.tpeT[2 * f + 1][tid + 256] = 0.5f * __cosf(a1);
            }
        }
        __syncthreads();

        const int ra = r0 + wave * 2, rb = ra + 1;
        float qa[16], qb[16];
#pragma unroll
        for (int f = 0; f < 16; f++) { qa[f] = sm.e.tpeT[f][ra]; qb[f] = sm.e.tpeT[f][rb]; }

        unsigned* Ea = (unsigned*)(E16 + ((size_t)(b * S_) + ra) * S_);
        unsigned* Eb = (unsigned*)(E16 + ((size_t)(b * S_) + rb) * S_);
#pragma unroll
        for (int j = 0; j < 4; j++) {
            int k0 = j * 128 + lane * 2;
            float a0 = 0.f, a1 = 0.f, b0 = 0.f, b1 = 0.f;
#pragma unroll
            for (int f = 0; f < 16; f++) {
                float2 kv = *(const float2*)&sm.e.tpeT[f][k0];
                a0 += qa[f] * kv.x; a1 += qa[f] * kv.y;
                b0 += qb[f] * kv.x; b1 += qb[f] * kv.y;
            }
            unsigned ea0 = f2bf(__expf(a0 - 2.0f)), ea1 = f2bf(__expf(a1 - 2.0f));
            unsigned eb0 = f2bf(__expf(b0 - 2.0f)), eb1 = f2bf(__expf(b1 - 2.0f));
            Ea[j * 64 + lane] = ea0 | (ea1 << 16);
            Eb[j * 64 + lane] = eb0 | (eb1 << 16);
        }
    } else {
        // ================= Bprep + copy part =================
        const int j = bid - 512;
        const int bp = j >> 1;
        const int kh = j & 1;            // half of the K range (4 chunks each)

        const float* maskBP = mask + (size_t)bp * S_;
        for (int i = tid; i < S_; i += 256) sm.p.maskL[i] = maskBP[i];

        const float4* x4 = (const float4*)(x + (size_t)bp * S_ * D_);
        float4* out4 = (float4*)(out + (size_t)bp * S_ * D_);
        unsigned short* Bp = Bprep + (size_t)bp * 40960;

        for (int cc = kh * 4; cc < kh * 4 + 4; cc++) {
            const int k0 = cc * 64;
            __syncthreads();   // xbT reuse from previous chunk (and maskL on first)
            // load x chunk coalesced; copy mask=1 rows to out; transpose-store bf16(mask*x)
#pragma unroll
            for (int it = 0; it < 4; it++) {
                int i4 = tid + it * 256;
                int kl = i4 >> 4, c4 = i4 & 15;
                int k = k0 + kl;
                float4 g = x4[k * 16 + c4];
                float mv = sm.p.maskL[k];
                if (mv >= 0.5f) out4[k * 16 + c4] = g;
                sm.p.xbT[c4 * 4 + 0][kl] = f2bf(g.x * mv);
                sm.p.xbT[c4 * 4 + 1][kl] = f2bf(g.y * mv);
                sm.p.xbT[c4 * 4 + 2][kl] = f2bf(g.z * mv);
                sm.p.xbT[c4 * 4 + 3][kl] = f2bf(g.w * mv);
            }
            __syncthreads();
            // emit 640 short8 items: (kc2<2, ct<5, lane l<64)
            for (int e = tid; e < 640; e += 256) {
                int l = e & 63;
                int ctk = e >> 6;                 // kc2*5 + ct
                int kc2 = ctk >= 5 ? 1 : 0;
                int ct = ctk - kc2 * 5;
                int qd = l >> 4, nl = l & 15;
                short8 w;
                if (ct == 4) {                    // mask tile: col 0 = mask, rest 0
#pragma unroll
                    for (int jj = 0; jj < 8; jj++) {
                        int k = k0 + kc2 * 32 + qd * 8 + jj;
                        w[jj] = (nl == 0) ? (short)f2bf(sm.p.maskL[k]) : (short)0;
                    }
                } else {
                    w = *(const short8*)&sm.p.xbT[ct * 16 + nl][kc2 * 32 + qd * 8];
                }
                *(short8*)&Bp[((size_t)(cc * 2 + kc2) * 5 + ct) * 512 + l * 8] = w;
            }
        }
    }
}

// ---------------------------------------------------------------------------
// Kernel 2: barrier-free MFMA attention. Grid 1024 = b + 8*(p + 32*q),
// 256 threads (4 waves). Query rows only (mask=0); keys uncompacted (masked
// keys are zeros in Bprep). A-frags from E16 (global), B-frags from Bprep
// (global, B-fragment lane order, L1-shared across the block's waves).
// Denominator = MFMA tile ct=4 col 0; self term E[s][s] == 1 exactly.
// ---------------------------------------------------------------------------
__launch_bounds__(256, 4)
__global__ void k_attn6(const float* __restrict__ x, const float* __restrict__ mask,
                        const unsigned short* __restrict__ E16,
                        const unsigned short* __restrict__ Bprep,
                        float* __restrict__ out) {
    const int bid = blockIdx.x;
    const int b = bid & 7;
    const int rdec = bid >> 3;
    const int p = rdec & 31;
    const int q = rdec >> 5;               // 0..3
    const int bp = b * P_ + p;
    const int tid = threadIdx.x, lane = tid & 63, wave = tid >> 6;
    const int quad = lane >> 4, nlane = lane & 15;

    __shared__ short qidxL[S_];
    __shared__ int cntS;

    const float* maskBP = mask + (size_t)bp * S_;
    const float* xBP = x + (size_t)bp * S_ * D_;
    float* outBP = out + (size_t)bp * S_ * D_;
    const unsigned short* Eb = E16 + (size_t)b * S_ * S_;
    const unsigned short* BpL = Bprep + (size_t)bp * 40960 + lane * 8;

    // build compacted query (mask=0) list — wave 0 only, global reads
    if (wave == 0) {
        int nq = 0;
        for (int c = 0; c < 8; c++) {
            int tt = c * 64 + lane;
            bool isq = maskBP[tt] < 0.5f;
            unsigned long long bm = __ballot(isq);
            int pb = __popcll(bm & ((1ull << lane) - 1ull));
            if (isq) qidxL[nq + pb] = (short)tt;
            nq += __popcll(bm);
        }
        if (lane == 0) cntS = nq;
    }
    __syncthreads();   // the only barrier
    const int NQ = cntS;

    const int qq = (NQ + NQS - 1) / NQS;
    const int qb0 = q * qq;
    const int rows = min(NQ, qb0 + qq) - qb0;
    if (rows <= 0) return;
    const int NT = (rows + 15) >> 4;

    for (int ti = wave; ti < NT; ti += 4) {
        const unsigned short* Arow;
        {
            int rowl = min(ti * 16 + nlane, rows - 1);
            Arow = Eb + (size_t)qidxL[qb0 + rowl] * S_;
        }
        f32x4 acc[5];
#pragma unroll
        for (int ct = 0; ct < 5; ct++) acc[ct] = (f32x4){0.f, 0.f, 0.f, 0.f};

#pragma unroll
        for (int c = 0; c < 8; c++) {
            short8 a0 = *(const short8*)(Arow + c * 64 + quad * 8);
            short8 a1 = *(const short8*)(Arow + c * 64 + 32 + quad * 8);
#pragma unroll
            for (int ct = 0; ct < 5; ct++) {
                short8 b0 = *(const short8*)(BpL + ((c * 2 + 0) * 5 + ct) * 512);
                short8 b1 = *(const short8*)(BpL + ((c * 2 + 1) * 5 + ct) * 512);
                acc[ct] = __builtin_amdgcn_mfma_f32_16x16x32_bf16(a0, b0, acc[ct], 0, 0, 0);
                acc[ct] = __builtin_amdgcn_mfma_f32_16x16x32_bf16(a1, b1, acc[ct], 0, 0, 0);
            }
        }

        // epilogue: den from mask tile col 0; self term weight == 1 exactly
#pragma unroll
        for (int reg = 0; reg < 4; reg++) {
            float den = __shfl(acc[4][reg], lane & 48, 64);
            int rowl = ti * 16 + quad * 4 + reg;
            if (rowl < rows) {
                int sg = qidxL[qb0 + rowl];
                float inv = 1.0f / (den + 1.0f);
#pragma unroll
                for (int ct = 0; ct < 4; ct++) {
                    int col = ct * 16 + nlane;
                    float xv = xBP[(size_t)sg * D_ + col];
                    outBP[(size_t)sg * D_ + col] = (acc[ct][reg] + xv) * inv;
                }
            }
        }
    }
}

// ---------------------------------------------------------------------------
extern "C" void kernel_launch(void* const* d_in, const int* in_sizes, int n_in,
                              void* d_out, int out_size, void* d_ws, size_t ws_size,
                              hipStream_t stream) {
    const float* t       = (const float*)d_in[0]; // (B,S)
    const float* x       = (const float*)d_in[1]; // (B,P,S,D)
    const float* mask    = (const float*)d_in[2]; // (B,P,S)
    const float* alpha_w = (const float*)d_in[3]; // (1,1)
    float* out = (float*)d_out;

    // ws: E16 (B*S*S bf16 = 4 MB) | Bprep (256 bp * 80 KB = 20 MB)
    unsigned short* E16   = (unsigned short*)d_ws;
    unsigned short* Bprep = (unsigned short*)((char*)d_ws + (size_t)B_ * S_ * S_ * 2);

    k_prep<<<dim3(1024), dim3(256), 0, stream>>>(t, alpha_w, x, mask, E16, Bprep, out);
    k_attn6<<<dim3(B_ * P_ * NQS), dim3(256), 0, stream>>>(x, mask, E16, Bprep, out);
}

// Round 7
// 116.316 us; speedup vs baseline: 2.2859x; 2.2859x over previous
//
#include <hip/hip_runtime.h>
#include <math.h>

#define B_ 8
#define P_ 32
#define S_ 512
#define D_ 64
#define NP 2     // query-tile pairs per wave (covers NQ up to 512)

typedef __attribute__((ext_vector_type(8))) short short8;
typedef __attribute__((ext_vector_type(4))) float f32x4;

static __device__ inline unsigned short f2bf(float f) {
    // round-to-nearest-even fp32 -> bf16 (finite inputs only)
    unsigned u = __float_as_uint(f);
    unsigned r = (u + 0x7FFFu + ((u >> 16) & 1u)) >> 16;
    return (unsigned short)r;
}

// ---------------------------------------------------------------------------
// Kernel 1: t -> min/max norm -> elu scale -> tpe (transposed in LDS) ->
// E16[b,r,k] = bf16(exp(score-2)). Grid (64, B). (Unchanged from R4 — proven.)
// ---------------------------------------------------------------------------
__launch_bounds__(256)
__global__ void k_scoresE2(const float* __restrict__ t, const float* __restrict__ alpha_w,
                           unsigned short* __restrict__ E16) {
    const int b = blockIdx.y;
    const int r0 = blockIdx.x * 8;
    const int tid = threadIdx.x, lane = tid & 63, wave = tid >> 6;

    __shared__ float tpeT[16][S_];
    __shared__ float red[8];

    float v0 = t[b * S_ + tid];
    float v1 = t[b * S_ + tid + 256];
    float mn = fminf(v0, v1), mx = fmaxf(v0, v1);
#pragma unroll
    for (int o = 32; o > 0; o >>= 1) {
        mn = fminf(mn, __shfl_xor(mn, o, 64));
        mx = fmaxf(mx, __shfl_xor(mx, o, 64));
    }
    if (lane == 0) { red[wave] = mn; red[4 + wave] = mx; }
    __syncthreads();
    mn = fminf(fminf(red[0], red[1]), fminf(red[2], red[3]));
    mx = fmaxf(fmaxf(red[4], red[5]), fmaxf(red[6], red[7]));

    float aw = alpha_w[0] * 1000.0f;
    float el = aw > 0.0f ? aw : (__expf(aw) - 1.0f);   // elu, alpha=1
    float inv = (el + 1.0f) / (mx - mn);

    const float divs[8] = {1.0f, 0.31622776601683794f, 0.1f, 0.031622776601683791f,
                           0.01f, 0.0031622776601683794f, 0.001f, 0.00031622776601683794f};
    {
        float tn0 = (v0 - mn) * inv;
        float tn1 = (v1 - mn) * inv;
#pragma unroll
        for (int f = 0; f < 8; f++) {
            float a0 = tn0 * divs[f], a1 = tn1 * divs[f];
            tpeT[2 * f][tid]           = 0.5f * __sinf(a0);   // 0.5^2 folds /sqrt(16)
            tpeT[2 * f + 1][tid]       = 0.5f * __cosf(a0);
            tpeT[2 * f][tid + 256]     = 0.5f * __sinf(a1);
            tpeT[2 * f + 1][tid + 256] = 0.5f * __cosf(a1);
        }
    }
    __syncthreads();

    const int ra = r0 + wave * 2, rb = ra + 1;
    float qa[16], qb[16];
#pragma unroll
    for (int f = 0; f < 16; f++) { qa[f] = tpeT[f][ra]; qb[f] = tpeT[f][rb]; }

    unsigned* Ea = (unsigned*)(E16 + ((size_t)(b * S_) + ra) * S_);
    unsigned* Eb = (unsigned*)(E16 + ((size_t)(b * S_) + rb) * S_);
#pragma unroll
    for (int j = 0; j < 4; j++) {
        int k0 = j * 128 + lane * 2;
        float a0 = 0.f, a1 = 0.f, b0 = 0.f, b1 = 0.f;
#pragma unroll
        for (int f = 0; f < 16; f++) {
            float2 kv = *(const float2*)&tpeT[f][k0];
            a0 += qa[f] * kv.x; a1 += qa[f] * kv.y;
            b0 += qb[f] * kv.x; b1 += qb[f] * kv.y;
        }
        unsigned ea0 = f2bf(__expf(a0 - 2.0f)), ea1 = f2bf(__expf(a1 - 2.0f));
        unsigned eb0 = f2bf(__expf(b0 - 2.0f)), eb1 = f2bf(__expf(b1 - 2.0f));
        Ea[j * 64 + lane] = ea0 | (ea1 << 16);
        Eb[j * 64 + lane] = eb0 | (eb1 << 16);
    }
}

// ---------------------------------------------------------------------------
// Kernel 2: MFMA attention, 1 block per bp (grid 256, XCD swizzle bid=b+8p),
// 512 threads (8 waves). B-operand (bf16(mask*x) + mask column, fragment
// order) staged in LDS ONCE, in two 256-key phases of a 40 KB single buffer.
// Each wave owns up to NP pairs of 16-row query tiles: one B ds_read feeds
// 2 MFMAs. Copy rows (mask=1) written during staging (wave-uniform, 256B
// coalesced). Denominator from mask-tile col 0; self-weight == 1 exactly.
// ---------------------------------------------------------------------------
__launch_bounds__(512, 2)
__global__ void k_attn7(const float* __restrict__ x, const float* __restrict__ mask,
                        const unsigned short* __restrict__ E16, float* __restrict__ out) {
    const int bid = blockIdx.x;
    const int b = bid & 7, p = bid >> 3;
    const int bp = b * P_ + p;
    const int tid = threadIdx.x, lane = tid & 63, wave = tid >> 6;
    const int quad = lane >> 4, nlane = lane & 15;
    const int kg = wave;   // staging: 32-key group per wave

    __shared__ float maskL[S_];
    __shared__ short qidxL[S_];
    __shared__ int cntS;
    __shared__ __align__(16) unsigned short Bfrag[8][5][64][8];   // 40 KB

    const float* maskBP = mask + (size_t)bp * S_;
    const float* xBP = x + (size_t)bp * S_ * D_;
    float* outBP = out + (size_t)bp * S_ * D_;
    const unsigned short* Eb = E16 + (size_t)b * S_ * S_;

    maskL[tid] = maskBP[tid];
    __syncthreads();

    // compacted query (mask=0) list
    if (wave == 0) {
        int nq = 0;
        for (int c = 0; c < 8; c++) {
            int tt = c * 64 + lane;
            bool isq = maskL[tt] < 0.5f;
            unsigned long long bm = __ballot(isq);
            int pb = __popcll(bm & ((1ull << lane) - 1ull));
            if (isq) qidxL[nq + pb] = (short)tt;
            nq += __popcll(bm);
        }
        if (lane == 0) cntS = nq;
    }
    __syncthreads();
    const int NQ = cntS;

    // pair setup: pair pi = wave + 8*i covers query rows [pi*32, pi*32+32)
    const unsigned short* Ar[NP][2];
    bool act[NP];
#pragma unroll
    for (int i = 0; i < NP; i++) {
        int pi = wave + 8 * i;
        act[i] = (pi * 32) < NQ;
        int r0 = act[i] ? min(pi * 32 + nlane, NQ - 1) : 0;
        int r1 = act[i] ? min(pi * 32 + 16 + nlane, NQ - 1) : 0;
        Ar[i][0] = Eb + (size_t)qidxL[r0] * S_;
        Ar[i][1] = Eb + (size_t)qidxL[r1] * S_;
    }

    f32x4 acc[NP][2][5];
#pragma unroll
    for (int i = 0; i < NP; i++)
#pragma unroll
        for (int tt = 0; tt < 2; tt++)
#pragma unroll
            for (int ct = 0; ct < 5; ct++) acc[i][tt][ct] = (f32x4){0.f, 0.f, 0.f, 0.f};

    for (int h = 0; h < 2; h++) {
        if (h) __syncthreads();   // compute(h-1) done reading Bfrag

        // ---- stage keys [h*256, h*256+256) ----
        {
            // mask column tile (ct=4): col 0 = mask, cols 1..15 = 0
            short8 w;
#pragma unroll
            for (int j = 0; j < 8; j++) {
                int k = h * 256 + kg * 32 + quad * 8 + j;
                w[j] = (nlane == 0) ? (short)f2bf(maskL[k]) : (short)0;
            }
            *(short8*)&Bfrag[kg][4][lane][0] = w;
        }
#pragma unroll
        for (int g = 0; g < 4; g++) {
            int kb = h * 256 + kg * 32 + g * 8;
            float v[8];
#pragma unroll
            for (int j = 0; j < 8; j++) v[j] = xBP[(size_t)(kb + j) * D_ + lane];
            short8 w;
#pragma unroll
            for (int j = 0; j < 8; j++) {
                float mv = maskL[kb + j];
                if (mv >= 0.5f) outBP[(size_t)(kb + j) * D_ + lane] = v[j];  // copy rows
                w[j] = (short)f2bf(v[j] * mv);
            }
            *(short8*)&Bfrag[kg][lane >> 4][g * 16 + nlane][0] = w;
        }
        __syncthreads();

        // ---- compute: 8 k-steps of 32, each B-read feeds 2 MFMAs ----
#pragma unroll
        for (int i = 0; i < NP; i++) {
            if (act[i]) {
#pragma unroll
                for (int kc2 = 0; kc2 < 8; kc2++) {
                    short8 a0 = *(const short8*)(Ar[i][0] + h * 256 + kc2 * 32 + quad * 8);
                    short8 a1 = *(const short8*)(Ar[i][1] + h * 256 + kc2 * 32 + quad * 8);
#pragma unroll
                    for (int ct = 0; ct < 5; ct++) {
                        short8 bb = *(const short8*)&Bfrag[kc2][ct][lane][0];
                        acc[i][0][ct] = __builtin_amdgcn_mfma_f32_16x16x32_bf16(a0, bb, acc[i][0][ct], 0, 0, 0);
                        acc[i][1][ct] = __builtin_amdgcn_mfma_f32_16x16x32_bf16(a1, bb, acc[i][1][ct], 0, 0, 0);
                    }
                }
            }
        }
    }

    // ---- epilogue: den from mask tile col 0; self weight == 1 exactly ----
#pragma unroll
    for (int i = 0; i < NP; i++) {
        if (!act[i]) continue;
#pragma unroll
        for (int tt = 0; tt < 2; tt++) {
#pragma unroll
            for (int reg = 0; reg < 4; reg++) {
                float den = __shfl(acc[i][tt][4][reg], lane & 48, 64);
                int rowl = (wave + 8 * i) * 32 + tt * 16 + quad * 4 + reg;
                if (rowl < NQ) {
                    int sg = qidxL[rowl];
                    float inv = 1.0f / (den + 1.0f);
#pragma unroll
                    for (int ct = 0; ct < 4; ct++) {
                        int col = ct * 16 + nlane;
                        float xv = xBP[(size_t)sg * D_ + col];
                        outBP[(size_t)sg * D_ + col] = (acc[i][tt][ct][reg] + xv) * inv;
                    }
                }
            }
        }
    }
}

// ---------------------------------------------------------------------------
extern "C" void kernel_launch(void* const* d_in, const int* in_sizes, int n_in,
                              void* d_out, int out_size, void* d_ws, size_t ws_size,
                              hipStream_t stream) {
    const float* t       = (const float*)d_in[0]; // (B,S)
    const float* x       = (const float*)d_in[1]; // (B,P,S,D)
    const float* mask    = (const float*)d_in[2]; // (B,P,S)
    const float* alpha_w = (const float*)d_in[3]; // (1,1)
    float* out = (float*)d_out;

    unsigned short* E16 = (unsigned short*)d_ws;   // B*S*S bf16 = 4 MB

    k_scoresE2<<<dim3(S_ / 8, B_), dim3(256), 0, stream>>>(t, alpha_w, E16);
    k_attn7<<<dim3(B_ * P_), dim3(512), 0, stream>>>(x, mask, E16, out);
}

// Round 8
// 105.425 us; speedup vs baseline: 2.5221x; 1.1033x over previous
//
#include <hip/hip_runtime.h>
#include <math.h>

#define B_ 8
#define P_ 32
#define S_ 512
#define D_ 64

typedef __attribute__((ext_vector_type(4))) _Float16 half4;
typedef __attribute__((ext_vector_type(4))) float f32x4;

// ---------------------------------------------------------------------------
// Single fused kernel. Grid 256 (one block per bp), 512 threads (8 waves).
//
// Math: out[s] = x[s] if mask[s]=1 else (sum_k P[s][k]*mask[k]*x[k] + x[s]) /
//       (sum_k P[s][k]*mask[k] + 1), P = exp(score-2), score = tpe_s . tpe_k,
//       self-weight exp(score_ss-2) = exp(0) = 1 exactly since |tpe|^2 = 2.
//
// Layout trick: compute S^T = mfma16(A=tpe_key-frag, B=tpe_query-frag).
// S^T C-layout (lane: col q = lane&15, rows key = quad*4+reg) IS the
// B-fragment layout of the PV mfma16 (lane: col q = lane&15, k = quad*4+j):
// P stays in registers. PV: inter^T = mfma16(A = fp16(mask*x)^T frag, B = P).
// Mask-row A-tile (ct=4, m=0 row = mask) makes the denominator fall out of
// the same MFMA chain. x staged to LDS once, double-buffered 64-key chunks.
// ---------------------------------------------------------------------------
__launch_bounds__(512, 2)
__global__ void k_fused(const float* __restrict__ t, const float* __restrict__ alpha_w,
                        const float* __restrict__ x, const float* __restrict__ mask,
                        float* __restrict__ out) {
    const int bp = blockIdx.x;
    const int b = bp >> 5;
    const int tid = threadIdx.x, lane = tid & 63, wave = tid >> 6;
    const int quad = lane >> 4, nl = lane & 15;

    __shared__ float maskL[S_];
    __shared__ short qidxL[S_];
    __shared__ int cntS;
    __shared__ float red[16];
    __shared__ __align__(16) _Float16 tpeP[S_][24];            // 24 KB (16 + 8 pad)
    __shared__ __align__(16) _Float16 Xfrag[2][4][5][64][4];   // 20.5 KB

    const float* maskBP = mask + (size_t)bp * S_;
    const float* xBP = x + (size_t)bp * S_ * D_;
    float* outBP = out + (size_t)bp * S_ * D_;

    // ---- load t + mask, min/max reduce ----
    float tv = t[b * S_ + tid];
    maskL[tid] = maskBP[tid];
    {
        float mn = tv, mx = tv;
#pragma unroll
        for (int o = 32; o > 0; o >>= 1) {
            mn = fminf(mn, __shfl_xor(mn, o, 64));
            mx = fmaxf(mx, __shfl_xor(mx, o, 64));
        }
        if (lane == 0) { red[wave] = mn; red[8 + wave] = mx; }
    }
    __syncthreads();   // B1
    float mn = red[0], mx = red[8];
#pragma unroll
    for (int w = 1; w < 8; w++) { mn = fminf(mn, red[w]); mx = fmaxf(mx, red[8 + w]); }

    float aw = alpha_w[0] * 1000.0f;
    float el = aw > 0.0f ? aw : (__expf(aw) - 1.0f);   // elu, alpha=1
    float inv = (el + 1.0f) / (mx - mn);

    // ---- tpe row tid (pre-scaled by 0.5 so dot = score/4) ----
    {
        const float divs[8] = {1.0f, 0.31622776601683794f, 0.1f, 0.031622776601683791f,
                               0.01f, 0.0031622776601683794f, 0.001f, 0.00031622776601683794f};
        float tn = (tv - mn) * inv;
        half4 w[4];
#pragma unroll
        for (int f = 0; f < 8; f++) {
            float ang = tn * divs[f];
            w[f >> 1][(f & 1) * 2]     = (_Float16)(0.5f * __sinf(ang));
            w[f >> 1][(f & 1) * 2 + 1] = (_Float16)(0.5f * __cosf(ang));
        }
#pragma unroll
        for (int g = 0; g < 4; g++) *(half4*)&tpeP[tid][g * 4] = w[g];
    }

    // ---- compacted query (mask=0) index list ----
    if (wave == 0) {
        int nq = 0;
        for (int c = 0; c < 8; c++) {
            int tt = c * 64 + lane;
            bool isq = maskL[tt] < 0.5f;
            unsigned long long bm = __ballot(isq);
            int pb = __popcll(bm & ((1ull << lane) - 1ull));
            if (isq) qidxL[nq + pb] = (short)tt;
            nq += __popcll(bm);
        }
        if (lane == 0) cntS = nq;
    }
    __syncthreads();   // B2
    const int NQ = cntS;

    // ---- per-wave query tiles: qt = wave + 8*i, i<3 (covers NQ <= 384) ----
    bool act[3];
    half4 bQ[3];
#pragma unroll
    for (int i = 0; i < 3; i++) {
        int qt = wave + 8 * i;
        act[i] = (qt * 16) < NQ;
        int rq = act[i] ? min(qt * 16 + nl, NQ - 1) : 0;
        int row = ((int)qidxL[rq]) & (S_ - 1);
        bQ[i] = *(const half4*)&tpeP[row][quad * 4];
    }

    f32x4 acc[3][5];
#pragma unroll
    for (int i = 0; i < 3; i++)
#pragma unroll
        for (int ct = 0; ct < 5; ct++) acc[i][ct] = (f32x4){0.f, 0.f, 0.f, 0.f};

    // staging helpers: chunk = 64 keys = 4 kt-tiles of 16
    auto issue = [&](int kb, float v[2][4]) {
#pragma unroll
        for (int it = 0; it < 2; it++) {
            int item = it * 512 + tid;
            int d = item & 63, qd = (item >> 6) & 3, kt = (item >> 8) & 3;
            int key = kb + kt * 16 + qd * 4;
            const float* base = xBP + (size_t)key * D_ + d;
#pragma unroll
            for (int j = 0; j < 4; j++) v[it][j] = base[j * D_];
        }
    };
    auto commit = [&](int buf, int kb, float v[2][4]) {
#pragma unroll
        for (int it = 0; it < 2; it++) {
            int item = it * 512 + tid;
            int d = item & 63, qd = (item >> 6) & 3, kt = (item >> 8) & 3;
            int key = kb + kt * 16 + qd * 4;
            half4 w;
#pragma unroll
            for (int j = 0; j < 4; j++) {
                float mv = maskL[key + j];
                if (mv >= 0.5f) outBP[(size_t)(key + j) * D_ + d] = v[it][j];  // copy rows
                w[j] = (_Float16)(v[it][j] * mv);
            }
            *(half4*)&Xfrag[buf][kt][d >> 4][qd * 16 + (d & 15)][0] = w;
        }
        if (tid < 256) {   // mask A-tile (ct=4): row m=0 = mask, rows 1..15 = 0
            int kt = tid >> 6, l = tid & 63;
            int qd = l >> 4, m = l & 15;
            half4 w;
#pragma unroll
            for (int j = 0; j < 4; j++)
                w[j] = (m == 0) ? (_Float16)maskL[kb + kt * 16 + qd * 4 + j] : (_Float16)0.f;
            *(half4*)&Xfrag[buf][kt][4][l][0] = w;
        }
    };

    float v0[2][4];
    issue(0, v0);
    commit(0, 0, v0);
    __syncthreads();   // B3

    for (int c = 0; c < 8; c++) {
        float vn[2][4];
        if (c < 7) issue((c + 1) * 64, vn);

        const int buf = c & 1, kb = c * 64;
#pragma unroll
        for (int kt = 0; kt < 4; kt++) {
            half4 aK = *(const half4*)&tpeP[kb + kt * 16 + nl][quad * 4];
            half4 xA[5];
#pragma unroll
            for (int ct = 0; ct < 5; ct++)
                xA[ct] = *(const half4*)&Xfrag[buf][kt][ct][lane][0];
#pragma unroll
            for (int i = 0; i < 3; i++) {
                if (act[i]) {
                    f32x4 sT = __builtin_amdgcn_mfma_f32_16x16x16f16(
                        aK, bQ[i], (f32x4){0.f, 0.f, 0.f, 0.f}, 0, 0, 0);
                    half4 pt;
#pragma unroll
                    for (int j = 0; j < 4; j++) pt[j] = (_Float16)__expf(sT[j] - 2.0f);
#pragma unroll
                    for (int ct = 0; ct < 5; ct++)
                        acc[i][ct] = __builtin_amdgcn_mfma_f32_16x16x16f16(
                            xA[ct], pt, acc[i][ct], 0, 0, 0);
                }
            }
        }

        if (c < 7) commit(buf ^ 1, (c + 1) * 64, vn);
        __syncthreads();
    }

    // ---- epilogue: inter^T tiles (lane: col q = nl, rows d = quad*4+reg) ----
#pragma unroll
    for (int i = 0; i < 3; i++) {
        if (!act[i]) continue;
        int qt = wave + 8 * i;
        float den = __shfl(acc[i][4][0], nl, 64);   // D[m=0][q] from quad-0 lane
        float invd = 1.0f / (den + 1.0f);           // + self weight (exactly 1)
        int rowl = qt * 16 + nl;
        if (rowl < NQ) {
            int sg = qidxL[rowl];
#pragma unroll
            for (int ct = 0; ct < 4; ct++) {
                const float4 xv = *(const float4*)(xBP + (size_t)sg * D_ + ct * 16 + quad * 4);
                float4 o;
                o.x = (acc[i][ct][0] + xv.x) * invd;
                o.y = (acc[i][ct][1] + xv.y) * invd;
                o.z = (acc[i][ct][2] + xv.z) * invd;
                o.w = (acc[i][ct][3] + xv.w) * invd;
                *(float4*)(outBP + (size_t)sg * D_ + ct * 16 + quad * 4) = o;
            }
        }
    }
}

// ---------------------------------------------------------------------------
extern "C" void kernel_launch(void* const* d_in, const int* in_sizes, int n_in,
                              void* d_out, int out_size, void* d_ws, size_t ws_size,
                              hipStream_t stream) {
    const float* t       = (const float*)d_in[0]; // (B,S)
    const float* x       = (const float*)d_in[1]; // (B,P,S,D)
    const float* mask    = (const float*)d_in[2]; // (B,P,S)
    const float* alpha_w = (const float*)d_in[3]; // (1,1)
    float* out = (float*)d_out;

    k_fused<<<dim3(B_ * P_), dim3(512), 0, stream>>>(t, alpha_w, x, mask, out);
}